// Round 1
// baseline (581.917 us; speedup 1.0000x reference)
//
#include <hip/hip_runtime.h>
#include <hip/hip_bf16.h>

// B=2, L=4096, C=512, H=8, hd=64. f32 in/out; bf16 MFMA compute.
// v9: PV via 16x16x16 MFMA -- QK's C/D layout (keys at quad*4+r per lane)
// IS the 16x16x16 B-fragment layout (k = quad*4+e), so the exp output feeds
// PV directly in registers. The entire P LDS round-trip (write+read+parity
// pipeline, 6.5M bank-conflict cycles) is deleted. K double-buffered in
// regs, V single-buffered (issued at chunk top, used after qk+exp).
// exp folded to exp2 (log2e pre-scaled into q). qkv_rope: vt stores staged
// through LDS and written transposed as coalesced 16B (was 2B/8KB scatter).

typedef __attribute__((ext_vector_type(8))) short short8;    // 8 bf16
typedef __attribute__((ext_vector_type(4))) short short4v;   // 4 bf16
typedef __attribute__((ext_vector_type(4))) float floatx4;   // MFMA C/D

#define MFMA(a, b, c)   __builtin_amdgcn_mfma_f32_16x16x32_bf16((a), (b), (c), 0, 0, 0)
#define MFMA16(a, b, c) __builtin_amdgcn_mfma_f32_16x16x16bf16_1k((a), (b), (c), 0, 0, 0)

__device__ __forceinline__ unsigned short f2bf(float f) {
    unsigned int u = __builtin_bit_cast(unsigned int, f);
    return (unsigned short)((u + 0x7fffu + ((u >> 16) & 1u)) >> 16);  // RTNE
}
__device__ __forceinline__ unsigned int pack2(float lo, float hi) {
    __hip_bfloat162 h = __float22bfloat162_rn(make_float2(lo, hi));  // 1 instr
    unsigned int r;
    __builtin_memcpy(&r, &h, 4);
    return r;
}

__global__ __launch_bounds__(256) void conv_bf16(
    const float* __restrict__ src, ushort* __restrict__ dst, int n8)
{
    int i = blockIdx.x * blockDim.x + threadIdx.x;
    if (i >= n8) return;
    const float4* s = (const float4*)src + (size_t)i * 2;
    float4 a = s[0], b = s[1];
    uint4 r = { pack2(a.x, a.y), pack2(a.z, a.w), pack2(b.x, b.y), pack2(b.z, b.w) };
    *(uint4*)(dst + (size_t)i * 8) = r;
}

// RoPE LUT: lut[pos*32+j] = {cos, sin}(pos * 10000^(-j/32))
__global__ __launch_bounds__(256) void build_rope(float2* __restrict__ lut) {
    int i = blockIdx.x * 256 + threadIdx.x;   // 131072 entries
    int pos = i >> 5, j = i & 31;
    float invf = exp2f(-0.41524101186f * (float)j);
    float s, c;
    sincosf((float)pos * invf, &s, &c);
    lut[i] = make_float2(c, s);
}

// ---------------------------------------------------------------------------
// qkv = xb @ wb.T + b for G heads from h0; RoPE q,k (LUT); q pre-scaled by
// 0.125*log2e (flash uses exp2); v transposed (hd, L) via LDS tile so the
// global store is coalesced 16B (direct store was a 2B/8KB-stride scatter).
// Wave tile 32(M) x 64(N), block M=128.
// ---------------------------------------------------------------------------
__global__ __launch_bounds__(256) void qkv_rope(
    const ushort* __restrict__ xb,    // (8192, 512) bf16
    const ushort* __restrict__ wb,    // (1536, 512) bf16
    const float* __restrict__ bias,   // (1536,) f32
    const float2* __restrict__ lut,   // (4096, 32)
    ushort* __restrict__ q, ushort* __restrict__ k, ushort* __restrict__ vt,
    int G, int h0)
{
    __shared__ __align__(16) ushort vtile[64][136];   // 17408 B (sec==2 only)
    const int w_id = threadIdx.x >> 6;
    const int lane = threadIdx.x & 63;
    const int lr = lane & 15, quad = lane >> 4;
    const int m0 = blockIdx.x * 128 + w_id * 32;
    const int sec = blockIdx.y / G, hl = blockIdx.y % G;
    const int wc0 = sec * 512 + (h0 + hl) * 64;

    floatx4 acc[2][4] = {};
    const ushort* xrow0 = xb + (size_t)(m0 + lr) * 512 + quad * 8;
    const ushort* xrow1 = xb + (size_t)(m0 + 16 + lr) * 512 + quad * 8;
    for (int kk = 0; kk < 512; kk += 32) {
        short8 a0 = *(const short8*)(xrow0 + kk);
        short8 a1 = *(const short8*)(xrow1 + kk);
#pragma unroll
        for (int nt = 0; nt < 4; ++nt) {
            short8 b = *(const short8*)(wb + (size_t)(wc0 + nt * 16 + lr) * 512 + kk + quad * 8);
            acc[0][nt] = MFMA(a0, b, acc[0][nt]);
            acc[1][nt] = MFMA(a1, b, acc[1][nt]);
        }
    }

    if (sec < 2) {
#pragma unroll
        for (int mt = 0; mt < 2; ++mt)
#pragma unroll
            for (int nt = 0; nt < 4; ++nt) {
                const int d = nt * 16 + lr;
                const float bv = bias[wc0 + d];
#pragma unroll
                for (int r = 0; r < 4; ++r) {
                    const int row = m0 + mt * 16 + quad * 4 + r;
                    const int b_ = row >> 12;
                    const int pos = row & 4095;
                    float val = acc[mt][nt][r] + bv;
                    const size_t bhl = (size_t)(b_ * G + hl);
                    float partner = __shfl_xor(val, 1);
                    float2 cs = lut[(pos << 5) | (d & 31)];
                    float rh = (d & 1) ? partner : -partner;   // rotate_half
                    float rv = val * cs.x + rh * cs.y;
                    if (sec == 0) rv *= 0.18033688011112042f;  // 0.125*log2(e)
                    ushort* dst = (sec == 0) ? q : k;
                    dst[(bhl * 4096 + pos) * 64 + d] = f2bf(rv);
                }
            }
    } else {
        // v: stage bf16 tile (64 d x 128 pos) in LDS, store transposed 16B.
#pragma unroll
        for (int mt = 0; mt < 2; ++mt)
#pragma unroll
            for (int nt = 0; nt < 4; ++nt) {
                const int d = nt * 16 + lr;
                const float bv = bias[wc0 + d];
                short4v v4;
#pragma unroll
                for (int r = 0; r < 4; ++r)
                    v4[r] = (short)f2bf(acc[mt][nt][r] + bv);
                *(short4v*)&vtile[d][w_id * 32 + mt * 16 + quad * 4] = v4;
            }
        __syncthreads();
        const int m0b = blockIdx.x * 128;
        const int bb = m0b >> 12;
        const int pos0 = m0b & 4095;
        const size_t bhl = (size_t)(bb * G + hl);
#pragma unroll
        for (int i = 0; i < 4; ++i) {
            const int d = i * 16 + (threadIdx.x >> 4);
            const int pp = (threadIdx.x & 15) * 8;
            short8 vv = *(const short8*)&vtile[d][pp];
            *(short8*)(vt + (bhl * 64 + d) * 4096 + pos0 + pp) = vv;
        }
    }
}

// ---------------------------------------------------------------------------
// Flash v9. Block = 4 waves: w_id = qg + 2*kh. Wave = 32 queries
// (q0 = qtile*64 + qg*32) x 2048 keys (kh half) in 32-key chunks, no-max
// softmax (exp2; log2e folded into q). Per chunk: ldV(c) ; ldK(c+1) ;
// qk(c) x32-MFMA ; exp2 ; pv(c) x16-MFMA directly from registers.
// kh pair merges (O,l) via LDS. 1D grid: bhl = blockIdx.x % 2G (XCD-pinned).
// ---------------------------------------------------------------------------
__global__ __launch_bounds__(256, 4) void flash_attn(
    const ushort* __restrict__ q, const ushort* __restrict__ k,
    const ushort* __restrict__ vt, ushort* __restrict__ o,
    int G, int h0)
{
    __shared__ __align__(16) float mb[2][2176];   // 17408 B merge buffer
    const int w_id = threadIdx.x >> 6;
    const int lane = threadIdx.x & 63;
    const int lr = lane & 15, quad = lane >> 4;
    const int qg = w_id & 1, kh = w_id >> 1;
    const int nbh = 2 * G;
    const int bhl = blockIdx.x % nbh;
    const int qtile = blockIdx.x / nbh;
    const int b_ = bhl / G, hl = bhl % G;
    const int q0 = qtile * 64 + qg * 32;

    const ushort* qp = q + (size_t)bhl * 262144;
    const ushort* kp = k + (size_t)bhl * 262144;
    const ushort* vp = vt + (size_t)bhl * 262144;
    ushort* op = o + (size_t)b_ * 4096 * 512 + (size_t)(h0 + hl) * 64;

    // Q^T B-frags (q pre-scaled 0.125*log2e): qf[nn][c] = B[k=32c..][n=16nn+lr]
    short8 qf[2][2];
#pragma unroll
    for (int nn = 0; nn < 2; ++nn) {
        const ushort* qb = qp + (size_t)(q0 + 16 * nn + lr) * 64 + quad * 8;
        qf[nn][0] = *(const short8*)qb;
        qf[nn][1] = *(const short8*)(qb + 32);
    }

    floatx4 oacc[4][2] = {};   // [d-tile][n-tile]
    float lsum[2] = {0.f, 0.f};
    short8 ka0[2][2], ka1[2][2];
    short4v va[2][4];          // [k-subtile t][d-tile]: 4 keys each
    const int kbase = kh * 2048;

    // 32-bit element offsets from uniform bases (saddr-form loads)
    const int ko = (kbase + lr) * 64 + quad * 8;       // + c*2048 + t*1024 (+32)
    const int vo = lr * 4096 + kbase + quad * 4;       // + dt*65536 + c*32 + t*16

    auto ldK = [&](int c, short8 (&ka)[2][2]) {
        const ushort* kb = kp + ko + c * 2048;
#pragma unroll
        for (int t = 0; t < 2; ++t) {
            ka[t][0] = *(const short8*)(kb + t * 1024);
            ka[t][1] = *(const short8*)(kb + t * 1024 + 32);
        }
    };
    auto ldV = [&](int c) {
        const ushort* vb = vp + vo + c * 32;
#pragma unroll
        for (int t = 0; t < 2; ++t)
#pragma unroll
            for (int dt = 0; dt < 4; ++dt)
                va[t][dt] = *(const short4v*)(vb + dt * 65536 + t * 16);
    };
    auto process = [&](short8 (&ka)[2][2]) {
#pragma unroll
        for (int t = 0; t < 2; ++t) {
            floatx4 st[2];
#pragma unroll
            for (int nn = 0; nn < 2; ++nn) {
                floatx4 s = {};
                s = MFMA(ka[t][0], qf[nn][0], s);
                s = MFMA(ka[t][1], qf[nn][1], s);
                st[nn] = s;
            }
#pragma unroll
            for (int nn = 0; nn < 2; ++nn) {
                float p0 = exp2f(st[nn][0]), p1 = exp2f(st[nn][1]);
                float p2 = exp2f(st[nn][2]), p3 = exp2f(st[nn][3]);
                lsum[nn] += (p0 + p1) + (p2 + p3);
                uint2 u = { pack2(p0, p1), pack2(p2, p3) };
                short4v pf = __builtin_bit_cast(short4v, u);
#pragma unroll
                for (int dt = 0; dt < 4; ++dt)
                    oacc[dt][nn] = MFMA16(va[t][dt], pf, oacc[dt][nn]);
            }
        }
    };

    ldK(0, ka0);
    for (int it = 0; it < 62; it += 2) {
        ldV(it);
        ldK(it + 1, ka1);
        process(ka0);
        ldV(it + 1);
        ldK(it + 2, ka0);
        process(ka1);
    }
    ldV(62); ldK(63, ka1); process(ka0);   // chunk 62
    ldV(63); process(ka1);                  // chunk 63

    // l across quads (queries in lr; quads hold disjoint keys)
    lsum[0] += __shfl_xor(lsum[0], 16); lsum[0] += __shfl_xor(lsum[0], 32);
    lsum[1] += __shfl_xor(lsum[1], 16); lsum[1] += __shfl_xor(lsum[1], 32);

    __syncthreads();
    if (kh == 1) {
        float* m = &mb[qg][0];
#pragma unroll
        for (int dt = 0; dt < 4; ++dt)
#pragma unroll
            for (int nn = 0; nn < 2; ++nn)
#pragma unroll
                for (int r = 0; r < 4; ++r)
                    m[(16 * dt + 4 * quad + r) * 33 + 16 * nn + lr] = oacc[dt][nn][r];
        if (quad == 0) {
            m[2112 + lr] = lsum[0];
            m[2112 + 16 + lr] = lsum[1];
        }
    }
    __syncthreads();
    if (kh == 0) {
        float* m = &mb[qg][0];
        float inv0 = 1.0f / (lsum[0] + m[2112 + lr]);
        float inv1 = 1.0f / (lsum[1] + m[2112 + 16 + lr]);
#pragma unroll
        for (int dt = 0; dt < 4; ++dt)
#pragma unroll
            for (int nn = 0; nn < 2; ++nn) {
                float inv = nn ? inv1 : inv0;
                float v0 = (oacc[dt][nn][0] + m[(16 * dt + 4 * quad + 0) * 33 + 16 * nn + lr]) * inv;
                float v1 = (oacc[dt][nn][1] + m[(16 * dt + 4 * quad + 1) * 33 + 16 * nn + lr]) * inv;
                float v2 = (oacc[dt][nn][2] + m[(16 * dt + 4 * quad + 2) * 33 + 16 * nn + lr]) * inv;
                float v3 = (oacc[dt][nn][3] + m[(16 * dt + 4 * quad + 3) * 33 + 16 * nn + lr]) * inv;
                uint2 u = { pack2(v0, v1), pack2(v2, v3) };
                *(uint2*)(op + (size_t)(q0 + 16 * nn + lr) * 512 + 16 * dt + 4 * quad) = u;
            }
    }
}

// ---------------------------------------------------------------------------
// out(f32) = o(bf16) @ wb.T + proj_b. Wave tile 32(M) x 64(N).
// ---------------------------------------------------------------------------
__global__ __launch_bounds__(256) void proj_gemm(
    const ushort* __restrict__ o,      // (8192, 512) bf16
    const ushort* __restrict__ wb,     // (512, 512) bf16
    const float* __restrict__ bias,    // (512,) f32
    float* __restrict__ out)           // (8192, 512) f32
{
    const int w_id = threadIdx.x >> 6;
    const int lane = threadIdx.x & 63;
    const int lr = lane & 15, quad = lane >> 4;
    const int m0 = blockIdx.x * 128 + w_id * 32;
    const int n0 = blockIdx.y * 64;

    floatx4 acc[2][4] = {};
    const ushort* orow0 = o + (size_t)(m0 + lr) * 512 + quad * 8;
    const ushort* orow1 = o + (size_t)(m0 + 16 + lr) * 512 + quad * 8;
    for (int kk = 0; kk < 512; kk += 32) {
        short8 a0 = *(const short8*)(orow0 + kk);
        short8 a1 = *(const short8*)(orow1 + kk);
#pragma unroll
        for (int nt = 0; nt < 4; ++nt) {
            short8 b = *(const short8*)(wb + (size_t)(n0 + nt * 16 + lr) * 512 + kk + quad * 8);
            acc[0][nt] = MFMA(a0, b, acc[0][nt]);
            acc[1][nt] = MFMA(a1, b, acc[1][nt]);
        }
    }
#pragma unroll
    for (int mt = 0; mt < 2; ++mt)
#pragma unroll
        for (int nt = 0; nt < 4; ++nt) {
            const int n = n0 + nt * 16 + lr;
            const float bv = bias[n];
#pragma unroll
            for (int r = 0; r < 4; ++r)
                out[(size_t)(m0 + mt * 16 + quad * 4 + r) * 512 + n] = acc[mt][nt][r] + bv;
        }
}

extern "C" void kernel_launch(void* const* d_in, const int* in_sizes, int n_in,
                              void* d_out, int out_size, void* d_ws, size_t ws_size,
                              hipStream_t stream)
{
    const float* x      = (const float*)d_in[0];
    const float* qkv_w  = (const float*)d_in[1];
    const float* qkv_b  = (const float*)d_in[2];
    const float* proj_w = (const float*)d_in[3];
    const float* proj_b = (const float*)d_in[4];
    float* out = (float*)d_out;

    const size_t MB = (size_t)1 << 20;
    ushort* base = (ushort*)d_ws;
    int G;
    ushort *xb, *o, *wb, *pwb, *q, *k, *vt;
    if (ws_size >= 34 * MB) {
        // G=8: single group -> o aliases xb (xb dead before flash runs)
        G = 8;
        xb = base; o = base;                 // 8 MiB shared
        wb  = base + 4194304;                // 1.5 MiB
        pwb = wb + 786432;                   // 0.5 MiB
        q   = pwb + 262144;
        k   = q + (size_t)G * 524288;
        vt  = k + (size_t)G * 524288;
    } else {
        G = (ws_size >= 30 * MB) ? 4 : (ws_size >= 24 * MB) ? 2 : 1;
        xb  = base;
        o   = base + 4194304;
        wb  = o + 4194304;
        pwb = wb + 786432;
        q   = pwb + 262144;
        k   = q + (size_t)G * 524288;
        vt  = k + (size_t)G * 524288;
    }

    // RoPE LUT in the head of d_out (1 MB) — dead before proj writes.
    float2* lut = (float2*)d_out;
    build_rope<<<512, 256, 0, stream>>>(lut);

    conv_bf16<<<2048, 256, 0, stream>>>(x, xb, 524288);
    conv_bf16<<<384, 256, 0, stream>>>(qkv_w, wb, 98304);
    conv_bf16<<<128, 256, 0, stream>>>(proj_w, pwb, 32768);

    for (int h0 = 0; h0 < 8; h0 += G) {
        qkv_rope<<<dim3(64, 3 * G), 256, 0, stream>>>(xb, wb, qkv_b, lut, q, k, vt, G, h0);
        flash_attn<<<64 * 2 * G, 256, 0, stream>>>(q, k, vt, o, G, h0);
    }
    proj_gemm<<<dim3(64, 8), 256, 0, stream>>>(o, pwb, proj_b, out);
}

// Round 2
// 411.975 us; speedup vs baseline: 1.4125x; 1.4125x over previous
//
#include <hip/hip_runtime.h>
#include <hip/hip_bf16.h>

// B=2, L=4096, C=512, H=8, hd=64. f32 in/out; bf16 MFMA compute.
// v10: v9 (register PV via 16x16x16 MFMA, no P LDS round-trip) with the
// spill fixed: launch_bounds(256,3) (v9's (256,4) cap=128 VGPR forced hot-
// loop scratch spills -> WRITE_SIZE 8->52 MB, dur 247->425us). V is now
// double-buffered like K (>=1 chunk slack on every load), and V's key order
// is permuted per 32-key chunk at qkv_rope write time so each (t0,t1) pair
// of PV fragments is one contiguous 16B load (8 instead of 16 V-loads/chunk,
// full-cache-line fetches).

typedef __attribute__((ext_vector_type(8))) short short8;    // 8 bf16
typedef __attribute__((ext_vector_type(4))) short short4v;   // 4 bf16
typedef __attribute__((ext_vector_type(4))) float floatx4;   // MFMA C/D

#define MFMA(a, b, c)   __builtin_amdgcn_mfma_f32_16x16x32_bf16((a), (b), (c), 0, 0, 0)
#define MFMA16(a, b, c) __builtin_amdgcn_mfma_f32_16x16x16bf16_1k((a), (b), (c), 0, 0, 0)

__device__ __forceinline__ unsigned short f2bf(float f) {
    unsigned int u = __builtin_bit_cast(unsigned int, f);
    return (unsigned short)((u + 0x7fffu + ((u >> 16) & 1u)) >> 16);  // RTNE
}
__device__ __forceinline__ unsigned int pack2(float lo, float hi) {
    __hip_bfloat162 h = __float22bfloat162_rn(make_float2(lo, hi));  // 1 instr
    unsigned int r;
    __builtin_memcpy(&r, &h, 4);
    return r;
}

__global__ __launch_bounds__(256) void conv_bf16(
    const float* __restrict__ src, ushort* __restrict__ dst, int n8)
{
    int i = blockIdx.x * blockDim.x + threadIdx.x;
    if (i >= n8) return;
    const float4* s = (const float4*)src + (size_t)i * 2;
    float4 a = s[0], b = s[1];
    uint4 r = { pack2(a.x, a.y), pack2(a.z, a.w), pack2(b.x, b.y), pack2(b.z, b.w) };
    *(uint4*)(dst + (size_t)i * 8) = r;
}

// RoPE LUT: lut[pos*32+j] = {cos, sin}(pos * 10000^(-j/32))
__global__ __launch_bounds__(256) void build_rope(float2* __restrict__ lut) {
    int i = blockIdx.x * 256 + threadIdx.x;   // 131072 entries
    int pos = i >> 5, j = i & 31;
    float invf = exp2f(-0.41524101186f * (float)j);
    float s, c;
    sincosf((float)pos * invf, &s, &c);
    lut[i] = make_float2(c, s);
}

// ---------------------------------------------------------------------------
// qkv = xb @ wb.T + b for G heads from h0; RoPE q,k (LUT); q pre-scaled by
// 0.125*log2e (flash uses exp2); v transposed (hd, L) via LDS tile, stored
// with keys PERMUTED within each 32-key chunk: position g*8 + t*4 + e holds
// key t*16 + g*4 + e  (g=quad group). Flash then reads one 16B fragment pair
// per (dt). Wave tile 32(M) x 64(N), block M=128.
// ---------------------------------------------------------------------------
__global__ __launch_bounds__(256) void qkv_rope(
    const ushort* __restrict__ xb,    // (8192, 512) bf16
    const ushort* __restrict__ wb,    // (1536, 512) bf16
    const float* __restrict__ bias,   // (1536,) f32
    const float2* __restrict__ lut,   // (4096, 32)
    ushort* __restrict__ q, ushort* __restrict__ k, ushort* __restrict__ vt,
    int G, int h0)
{
    __shared__ __align__(16) ushort vtile[64][136];   // 17408 B (sec==2 only)
    const int w_id = threadIdx.x >> 6;
    const int lane = threadIdx.x & 63;
    const int lr = lane & 15, quad = lane >> 4;
    const int m0 = blockIdx.x * 128 + w_id * 32;
    const int sec = blockIdx.y / G, hl = blockIdx.y % G;
    const int wc0 = sec * 512 + (h0 + hl) * 64;

    floatx4 acc[2][4] = {};
    const ushort* xrow0 = xb + (size_t)(m0 + lr) * 512 + quad * 8;
    const ushort* xrow1 = xb + (size_t)(m0 + 16 + lr) * 512 + quad * 8;
    for (int kk = 0; kk < 512; kk += 32) {
        short8 a0 = *(const short8*)(xrow0 + kk);
        short8 a1 = *(const short8*)(xrow1 + kk);
#pragma unroll
        for (int nt = 0; nt < 4; ++nt) {
            short8 b = *(const short8*)(wb + (size_t)(wc0 + nt * 16 + lr) * 512 + kk + quad * 8);
            acc[0][nt] = MFMA(a0, b, acc[0][nt]);
            acc[1][nt] = MFMA(a1, b, acc[1][nt]);
        }
    }

    if (sec < 2) {
#pragma unroll
        for (int mt = 0; mt < 2; ++mt)
#pragma unroll
            for (int nt = 0; nt < 4; ++nt) {
                const int d = nt * 16 + lr;
                const float bv = bias[wc0 + d];
#pragma unroll
                for (int r = 0; r < 4; ++r) {
                    const int row = m0 + mt * 16 + quad * 4 + r;
                    const int b_ = row >> 12;
                    const int pos = row & 4095;
                    float val = acc[mt][nt][r] + bv;
                    const size_t bhl = (size_t)(b_ * G + hl);
                    float partner = __shfl_xor(val, 1);
                    float2 cs = lut[(pos << 5) | (d & 31)];
                    float rh = (d & 1) ? partner : -partner;   // rotate_half
                    float rv = val * cs.x + rh * cs.y;
                    if (sec == 0) rv *= 0.18033688011112042f;  // 0.125*log2(e)
                    ushort* dst = (sec == 0) ? q : k;
                    dst[(bhl * 4096 + pos) * 64 + d] = f2bf(rv);
                }
            }
    } else {
        // v: stage bf16 tile (64 d x 128 pos) in LDS, store permuted + 16B.
#pragma unroll
        for (int mt = 0; mt < 2; ++mt)
#pragma unroll
            for (int nt = 0; nt < 4; ++nt) {
                const int d = nt * 16 + lr;
                const float bv = bias[wc0 + d];
                short4v v4;
#pragma unroll
                for (int r = 0; r < 4; ++r)
                    v4[r] = (short)f2bf(acc[mt][nt][r] + bv);
                *(short4v*)&vtile[d][w_id * 32 + mt * 16 + quad * 4] = v4;
            }
        __syncthreads();
        const int m0b = blockIdx.x * 128;
        const int bb = m0b >> 12;
        const int pos0 = m0b & 4095;
        const size_t bhl = (size_t)(bb * G + hl);
        const int tid = threadIdx.x;
#pragma unroll
        for (int i = 0; i < 4; ++i) {
            const int d = i * 16 + (tid >> 4);
            const int pp = (tid & 15) * 8;      // store position in tile
            const int cb = pp & ~31;            // 32-key chunk base
            const int g  = (pp >> 3) & 3;       // quad group
            short4v a = *(const short4v*)&vtile[d][cb + g * 4];        // t=0
            short4v b = *(const short4v*)&vtile[d][cb + 16 + g * 4];   // t=1
            short8 vv = __builtin_shufflevector(a, b, 0, 1, 2, 3, 4, 5, 6, 7);
            *(short8*)(vt + (bhl * 64 + d) * 4096 + pos0 + pp) = vv;
        }
    }
}

// ---------------------------------------------------------------------------
// Flash v10. Block = 4 waves: w_id = qg + 2*kh. Wave = 32 queries
// (q0 = qtile*64 + qg*32) x 2048 keys (kh half) in 32-key chunks, no-max
// softmax (exp2; log2e folded into q). Per chunk pair: prefetch K,V of the
// next pair (register double-buffer, >=1 chunk slack), then qk (x32 MFMA) ->
// exp2 -> pv (x16 MFMA) straight from registers. kh pair merges (O,l) via
// LDS. 1D grid: bhl = blockIdx.x % 2G (XCD-pinned for 2G=16).
// ---------------------------------------------------------------------------
__global__ __launch_bounds__(256, 3) void flash_attn(
    const ushort* __restrict__ q, const ushort* __restrict__ k,
    const ushort* __restrict__ vt, ushort* __restrict__ o,
    int G, int h0)
{
    __shared__ __align__(16) float mb[2][2176];   // 17408 B merge buffer
    const int w_id = threadIdx.x >> 6;
    const int lane = threadIdx.x & 63;
    const int lr = lane & 15, quad = lane >> 4;
    const int qg = w_id & 1, kh = w_id >> 1;
    const int nbh = 2 * G;
    const int bhl = blockIdx.x % nbh;
    const int qtile = blockIdx.x / nbh;
    const int b_ = bhl / G, hl = bhl % G;
    const int q0 = qtile * 64 + qg * 32;

    const ushort* qp = q + (size_t)bhl * 262144;
    const ushort* kp = k + (size_t)bhl * 262144;
    const ushort* vp = vt + (size_t)bhl * 262144;
    ushort* op = o + (size_t)b_ * 4096 * 512 + (size_t)(h0 + hl) * 64;

    // Q^T B-frags (q pre-scaled 0.125*log2e): qf[nn][c] = B[k=32c..][n=16nn+lr]
    short8 qf[2][2];
#pragma unroll
    for (int nn = 0; nn < 2; ++nn) {
        const ushort* qb = qp + (size_t)(q0 + 16 * nn + lr) * 64 + quad * 8;
        qf[nn][0] = *(const short8*)qb;
        qf[nn][1] = *(const short8*)(qb + 32);
    }

    floatx4 oacc[4][2] = {};   // [d-tile][n-tile]
    float lsum[2] = {0.f, 0.f};
    short8 ka0[2][2], ka1[2][2];
    short8 va0[4], va1[4];     // [d-tile]: low 4 = t0 frag, high 4 = t1 frag
    const int kbase = kh * 2048;

    // 32-bit element offsets from uniform bases (saddr-form loads)
    const int ko = (kbase + lr) * 64 + quad * 8;   // + c*2048 + t*1024 (+32)
    const int vo = lr * 4096 + kbase + quad * 8;   // + dt*65536 + c*32

    auto ldK = [&](int c, short8 (&ka)[2][2]) {
        const ushort* kb = kp + ko + c * 2048;
#pragma unroll
        for (int t = 0; t < 2; ++t) {
            ka[t][0] = *(const short8*)(kb + t * 1024);
            ka[t][1] = *(const short8*)(kb + t * 1024 + 32);
        }
    };
    auto ldV = [&](int c, short8 (&va)[4]) {
        const ushort* vb = vp + vo + c * 32;
#pragma unroll
        for (int dt = 0; dt < 4; ++dt)
            va[dt] = *(const short8*)(vb + dt * 65536);
    };
    auto process = [&](short8 (&ka)[2][2], short8 (&va)[4]) {
#pragma unroll
        for (int t = 0; t < 2; ++t) {
            floatx4 st[2];
#pragma unroll
            for (int nn = 0; nn < 2; ++nn) {
                floatx4 s = {};
                s = MFMA(ka[t][0], qf[nn][0], s);
                s = MFMA(ka[t][1], qf[nn][1], s);
                st[nn] = s;
            }
#pragma unroll
            for (int nn = 0; nn < 2; ++nn) {
                float p0 = exp2f(st[nn][0]), p1 = exp2f(st[nn][1]);
                float p2 = exp2f(st[nn][2]), p3 = exp2f(st[nn][3]);
                lsum[nn] += (p0 + p1) + (p2 + p3);
                uint2 u = { pack2(p0, p1), pack2(p2, p3) };
                short4v pf = __builtin_bit_cast(short4v, u);
#pragma unroll
                for (int dt = 0; dt < 4; ++dt) {
                    short4v vf0 = __builtin_shufflevector(va[dt], va[dt], 0, 1, 2, 3);
                    short4v vf1 = __builtin_shufflevector(va[dt], va[dt], 4, 5, 6, 7);
                    oacc[dt][nn] = MFMA16((t == 0) ? vf0 : vf1, pf, oacc[dt][nn]);
                }
            }
        }
    };

    ldK(0, ka0); ldV(0, va0);
    for (int it = 0; it < 62; it += 2) {
        ldK(it + 1, ka1); ldV(it + 1, va1);
        process(ka0, va0);
        ldK(it + 2, ka0); ldV(it + 2, va0);
        process(ka1, va1);
    }
    // chunks 0..61 done; 62 resident in ka0/va0
    ldK(63, ka1); ldV(63, va1);
    process(ka0, va0);   // chunk 62
    process(ka1, va1);   // chunk 63

    // l across quads (queries in lr; quads hold disjoint keys)
    lsum[0] += __shfl_xor(lsum[0], 16); lsum[0] += __shfl_xor(lsum[0], 32);
    lsum[1] += __shfl_xor(lsum[1], 16); lsum[1] += __shfl_xor(lsum[1], 32);

    __syncthreads();
    if (kh == 1) {
        float* m = &mb[qg][0];
#pragma unroll
        for (int dt = 0; dt < 4; ++dt)
#pragma unroll
            for (int nn = 0; nn < 2; ++nn)
#pragma unroll
                for (int r = 0; r < 4; ++r)
                    m[(16 * dt + 4 * quad + r) * 33 + 16 * nn + lr] = oacc[dt][nn][r];
        if (quad == 0) {
            m[2112 + lr] = lsum[0];
            m[2112 + 16 + lr] = lsum[1];
        }
    }
    __syncthreads();
    if (kh == 0) {
        float* m = &mb[qg][0];
        float inv0 = 1.0f / (lsum[0] + m[2112 + lr]);
        float inv1 = 1.0f / (lsum[1] + m[2112 + 16 + lr]);
#pragma unroll
        for (int dt = 0; dt < 4; ++dt)
#pragma unroll
            for (int nn = 0; nn < 2; ++nn) {
                float inv = nn ? inv1 : inv0;
                float v0 = (oacc[dt][nn][0] + m[(16 * dt + 4 * quad + 0) * 33 + 16 * nn + lr]) * inv;
                float v1 = (oacc[dt][nn][1] + m[(16 * dt + 4 * quad + 1) * 33 + 16 * nn + lr]) * inv;
                float v2 = (oacc[dt][nn][2] + m[(16 * dt + 4 * quad + 2) * 33 + 16 * nn + lr]) * inv;
                float v3 = (oacc[dt][nn][3] + m[(16 * dt + 4 * quad + 3) * 33 + 16 * nn + lr]) * inv;
                uint2 u = { pack2(v0, v1), pack2(v2, v3) };
                *(uint2*)(op + (size_t)(q0 + 16 * nn + lr) * 512 + 16 * dt + 4 * quad) = u;
            }
    }
}

// ---------------------------------------------------------------------------
// out(f32) = o(bf16) @ wb.T + proj_b. Wave tile 32(M) x 64(N).
// ---------------------------------------------------------------------------
__global__ __launch_bounds__(256) void proj_gemm(
    const ushort* __restrict__ o,      // (8192, 512) bf16
    const ushort* __restrict__ wb,     // (512, 512) bf16
    const float* __restrict__ bias,    // (512,) f32
    float* __restrict__ out)           // (8192, 512) f32
{
    const int w_id = threadIdx.x >> 6;
    const int lane = threadIdx.x & 63;
    const int lr = lane & 15, quad = lane >> 4;
    const int m0 = blockIdx.x * 128 + w_id * 32;
    const int n0 = blockIdx.y * 64;

    floatx4 acc[2][4] = {};
    const ushort* orow0 = o + (size_t)(m0 + lr) * 512 + quad * 8;
    const ushort* orow1 = o + (size_t)(m0 + 16 + lr) * 512 + quad * 8;
    for (int kk = 0; kk < 512; kk += 32) {
        short8 a0 = *(const short8*)(orow0 + kk);
        short8 a1 = *(const short8*)(orow1 + kk);
#pragma unroll
        for (int nt = 0; nt < 4; ++nt) {
            short8 b = *(const short8*)(wb + (size_t)(n0 + nt * 16 + lr) * 512 + kk + quad * 8);
            acc[0][nt] = MFMA(a0, b, acc[0][nt]);
            acc[1][nt] = MFMA(a1, b, acc[1][nt]);
        }
    }
#pragma unroll
    for (int mt = 0; mt < 2; ++mt)
#pragma unroll
        for (int nt = 0; nt < 4; ++nt) {
            const int n = n0 + nt * 16 + lr;
            const float bv = bias[n];
#pragma unroll
            for (int r = 0; r < 4; ++r)
                out[(size_t)(m0 + mt * 16 + quad * 4 + r) * 512 + n] = acc[mt][nt][r] + bv;
        }
}

extern "C" void kernel_launch(void* const* d_in, const int* in_sizes, int n_in,
                              void* d_out, int out_size, void* d_ws, size_t ws_size,
                              hipStream_t stream)
{
    const float* x      = (const float*)d_in[0];
    const float* qkv_w  = (const float*)d_in[1];
    const float* qkv_b  = (const float*)d_in[2];
    const float* proj_w = (const float*)d_in[3];
    const float* proj_b = (const float*)d_in[4];
    float* out = (float*)d_out;

    const size_t MB = (size_t)1 << 20;
    ushort* base = (ushort*)d_ws;
    int G;
    ushort *xb, *o, *wb, *pwb, *q, *k, *vt;
    if (ws_size >= 34 * MB) {
        // G=8: single group -> o aliases xb (xb dead before flash runs)
        G = 8;
        xb = base; o = base;                 // 8 MiB shared
        wb  = base + 4194304;                // 1.5 MiB
        pwb = wb + 786432;                   // 0.5 MiB
        q   = pwb + 262144;
        k   = q + (size_t)G * 524288;
        vt  = k + (size_t)G * 524288;
    } else {
        G = (ws_size >= 30 * MB) ? 4 : (ws_size >= 24 * MB) ? 2 : 1;
        xb  = base;
        o   = base + 4194304;
        wb  = o + 4194304;
        pwb = wb + 786432;
        q   = pwb + 262144;
        k   = q + (size_t)G * 524288;
        vt  = k + (size_t)G * 524288;
    }

    // RoPE LUT in the head of d_out (1 MB) — dead before proj writes.
    float2* lut = (float2*)d_out;
    build_rope<<<512, 256, 0, stream>>>(lut);

    conv_bf16<<<2048, 256, 0, stream>>>(x, xb, 524288);
    conv_bf16<<<384, 256, 0, stream>>>(qkv_w, wb, 98304);
    conv_bf16<<<128, 256, 0, stream>>>(proj_w, pwb, 32768);

    for (int h0 = 0; h0 < 8; h0 += G) {
        qkv_rope<<<dim3(64, 3 * G), 256, 0, stream>>>(xb, wb, qkv_b, lut, q, k, vt, G, h0);
        flash_attn<<<64 * 2 * G, 256, 0, stream>>>(q, k, vt, o, G, h0);
    }
    proj_gemm<<<dim3(64, 8), 256, 0, stream>>>(o, pwb, proj_b, out);
}